// Round 8
// baseline (12892.215 us; speedup 1.0000x reference)
//
#include <hip/hip_runtime.h>
#include <math.h>

#define BATCH   8
#define NPTS    32768
#define FDIM    32
#define NGROUP  1024
#define GSIZE   32
#define KLANE   8       // per-lane candidate list length in KNN

// Multi-block FPS: 8 blocks/batch x 512 thr x 8 pts/thr; 64 waves/batch act
// as INDEPENDENT consensus agents (no intra-block barriers at all).
#define NBLK    8
#define FTPB    512
#define CHUNK   (NPTS / NBLK)   // 4096 points per block
#define WSLOTS  64              // waves per batch

// Exact float32 distance in the reference's association: ((dx^2+dy^2)+dz^2),
// contraction blocked so bits match the numpy ref (argmax stability).
__device__ __forceinline__ float dist2f(float ax, float ay, float az,
                                        float bx, float by, float bz) {
  float dx = __fsub_rn(ax, bx);
  float dy = __fsub_rn(ay, by);
  float dz = __fsub_rn(az, bz);
  return __fadd_rn(__fadd_rn(__fmul_rn(dx, dx), __fmul_rn(dy, dy)),
                   __fmul_rn(dz, dz));
}

#define X8(M) M(0) M(1) M(2) M(3) M(4) M(5) M(6) M(7)

// ---------------------------------------------------------------------------
// Kernel A: FPS, barrier-free per-wave consensus.
// R6 post-mortem: time is in the serial chain (2 barriers + 2-level reduce +
// acquire-polls + LDS bcast + dependent coord load), not slot placement
// (XCD swizzle cut FETCH 4x, time unchanged). R7: every wave is its own
// agent -- wave argmax -> lane0 release-store packed candidate to its slot
// -> 64 lanes relaxed-poll the batch's 64 slots (1 slot/lane, __ballot all
// tags==t) -> in-register 64-way max = exact global argmax (numpy
// tie-break via 0x7FFF-idx in low bits). No __syncthreads, no LDS.
// Parity ping-pong (t&1) keeps a fast wave's t+1 store from clobbering a
// value a slow wave still needs at t (t+2 same-parity write requires all
// waves to have exited poll t -- their poll loads are complete by then).
// Relaxed polls are sufficient: the u64 slot IS the entire payload; coord
// array is read-only so the dependent c3[gp] load needs no ordering.
// ---------------------------------------------------------------------------
__global__ __launch_bounds__(FTPB) void fps_kernel(
    const float* __restrict__ coord,
    unsigned long long* __restrict__ slots,   // [2][BATCH][64], pre-zeroed
    int* __restrict__ s_idx_out) {
  const int gb    = blockIdx.x;        // 0..63
  const int b     = gb & 7;            // batch (XCD-local under %8 mapping)
  const int bk    = gb >> 3;           // block within batch
  const int tid   = threadIdx.x;
  const int lane  = tid & 63;
  const int wid   = tid >> 6;          // 0..7
  const int wslot = (bk << 3) | wid;   // 0..63, this wave's slot
  const float* __restrict__ c = coord + (size_t)b * NPTS * 3;
  const float3* __restrict__ c3 = (const float3*)c;

  const int pbase = bk * CHUNK + tid;  // + i*FTPB

#define DECL8(i) float x##i, y##i, z##i, d##i;
  X8(DECL8)
#undef DECL8

  // Init: load owned points, distance to batch point 0, local argmax
  // (ascending point index + strict > == np.argmax lowest-index tie-break).
  float qx = c[0], qy = c[1], qz = c[2];
  float bestv = -1.0f; int bestp = 0;
#define LOAD8(i) { int p = pbase + (i) * FTPB; float3 v = c3[p];            \
    x##i = v.x; y##i = v.y; z##i = v.z;                                      \
    float t2 = dist2f(v.x, v.y, v.z, qx, qy, qz); d##i = t2;                 \
    if (t2 > bestv) { bestv = t2; bestp = p; } }
  X8(LOAD8)
#undef LOAD8

  if (wslot == 0 && lane == 0) s_idx_out[b * NGROUP + 0] = 0;

  for (int t = 1; t < NGROUP; ++t) {
    // Wave argmax over this wave's 512 points (max value, tie -> min index).
    float v = bestv; int p = bestp;
    #pragma unroll
    for (int m = 1; m < 64; m <<= 1) {
      float ov = __shfl_xor(v, m, 64);
      int   op = __shfl_xor(p, m, 64);
      if (ov > v || (ov == v && op < p)) { v = ov; p = op; }
    }

    unsigned long long* base =
        slots + (size_t)(t & 1) * (BATCH * WSLOTS) + (b << 6);
    if (lane == 0) {
      unsigned long long pk = ((unsigned long long)t << 47)
                            | ((unsigned long long)__float_as_uint(v) << 15)
                            | (unsigned long long)(0x7FFF - p);
      __hip_atomic_store(base + wslot, pk, __ATOMIC_RELEASE,
                         __HIP_MEMORY_SCOPE_AGENT);
    }

    // Poll: lane i watches slot i until every slot carries tag t.
    unsigned long long pk2;
    do {
      pk2 = __hip_atomic_load(base + lane, __ATOMIC_RELAXED,
                              __HIP_MEMORY_SCOPE_AGENT);
    } while (__ballot((int)(pk2 >> 47) == t) != ~0ULL);

    // In-register 64-way max = global argmax (numpy tie-break).
    #pragma unroll
    for (int m = 1; m < 64; m <<= 1) {
      unsigned long long o = __shfl_xor(pk2, m, 64);
      if (o > pk2) pk2 = o;
    }
    const int gp = 0x7FFF - (int)(pk2 & 0x7FFF);
    if (wslot == 0 && lane == 0) s_idx_out[b * NGROUP + t] = gp;
    if (t == NGROUP - 1) break;

    // Fetch winner coords (uniform wave load, L2-resident) + update dists.
    float3 q = c3[gp];
    qx = q.x; qy = q.y; qz = q.z;
    bestv = -1.0f; bestp = 0;
#define UPD8(i) { float t2 = dist2f(x##i, y##i, z##i, qx, qy, qz);           \
    float nd = fminf(d##i, t2); d##i = nd;                                   \
    if (nd > bestv) { bestv = nd; bestp = pbase + (i) * FTPB; } }
    X8(UPD8)
#undef UPD8
  }
}

// ---------------------------------------------------------------------------
// Kernel B: one wave per sampled point. Brute-force 32-NN (per-lane sorted
// top-8 over its 512 strided points, then 32 wave-argmin extractions),
// then the feature-angle curvature and all 5 outputs.
// ---------------------------------------------------------------------------
__global__ __launch_bounds__(256) void knn_kernel(
    const float* __restrict__ coord, const float* __restrict__ feat,
    const int* __restrict__ labels, const int* __restrict__ s_idx_ws,
    float* __restrict__ out) {
  const int lane = threadIdx.x & 63;
  const int qid  = (blockIdx.x << 2) + (threadIdx.x >> 6);  // 0..8191
  const int b    = qid >> 10;
  const float* __restrict__ c = coord + (size_t)b * NPTS * 3;

  int sp = __builtin_amdgcn_readfirstlane(s_idx_ws[qid]);
  const int gq = b * NPTS + sp;
  const float qx = coord[(size_t)gq * 3 + 0];
  const float qy = coord[(size_t)gq * 3 + 1];
  const float qz = coord[(size_t)gq * 3 + 2];

  // Per-lane ascending top-8 (value, index), static indexing only.
  float lv[KLANE]; int li[KLANE];
  #pragma unroll
  for (int j = 0; j < KLANE; ++j) { lv[j] = 1e30f; li[j] = 0x7fffffff; }

  for (int s = 0; s < NPTS / 64; ++s) {
    int p = (s << 6) + lane;
    float3 v = ((const float3*)c)[p];
    float d2 = dist2f(v.x, v.y, v.z, qx, qy, qz);
    if (d2 < lv[KLANE - 1]) {
      // Branchless unrolled sorted insert; strict < keeps equal-distance
      // earlier (lower) indices first, matching lax.top_k tie order.
      #pragma unroll
      for (int j = KLANE - 1; j >= 1; --j) {
        bool up = d2 < lv[j - 1];
        float nv = up ? lv[j - 1] : ((d2 < lv[j]) ? d2 : lv[j]);
        int   ni = up ? li[j - 1] : ((d2 < lv[j]) ? p  : li[j]);
        lv[j] = nv; li[j] = ni;
      }
      if (d2 < lv[0]) { lv[0] = d2; li[0] = p; }
    }
  }

  // Extract the 32 globally smallest (ascending, tie -> lower index).
  // Round 0 is the query itself (d2 == 0), excluded from the angle mean
  // like angles[:, :, 1:].
  int nbp = 0;
  for (int r = 0; r < GSIZE; ++r) {
    float mv = lv[0]; int mp = li[0];
    #pragma unroll
    for (int m = 1; m < 64; m <<= 1) {
      float ov = __shfl_xor(mv, m, 64);
      int   op = __shfl_xor(mp, m, 64);
      if (ov < mv || (ov == mv && op < mp)) { mv = ov; mp = op; }
    }
    if (lane == r) nbp = mp;
    if (lv[0] == mv && li[0] == mp) {  // unique winner pops its head
      #pragma unroll
      for (int j = 0; j < KLANE - 1; ++j) { lv[j] = lv[j + 1]; li[j] = li[j + 1]; }
      lv[KLANE - 1] = 1e30f; li[KLANE - 1] = 0x7fffffff;
    }
  }

  // Angle for lanes 1..31: theta = 2*atan2(||a*|b| - |a|*b||, ||a*|b| + |a|*b||)
  const float* aRow = feat + (size_t)gq * FDIM;
  float my_a = (lane < FDIM) ? aRow[lane] : 0.0f;

  float ang = 0.0f;
  if (lane >= 1 && lane < GSIZE) {
    const float4* a4 = (const float4*)aRow;
    const float4* b4 = (const float4*)(feat + ((size_t)b * NPTS + nbp) * FDIM);
    float4 av[FDIM / 4], bv[FDIM / 4];
    float aa = 0.0f, bb = 0.0f;
    #pragma unroll
    for (int k = 0; k < FDIM / 4; ++k) {
      av[k] = a4[k]; bv[k] = b4[k];
      aa += av[k].x * av[k].x + av[k].y * av[k].y + av[k].z * av[k].z + av[k].w * av[k].w;
      bb += bv[k].x * bv[k].x + bv[k].y * bv[k].y + bv[k].z * bv[k].z + bv[k].w * bv[k].w;
    }
    float an = sqrtf(aa), bn = sqrtf(bb);
    float num2 = 0.0f, den2 = 0.0f;
    #pragma unroll
    for (int k = 0; k < FDIM / 4; ++k) {
      float n0 = av[k].x * bn - an * bv[k].x, dd0 = av[k].x * bn + an * bv[k].x;
      float n1 = av[k].y * bn - an * bv[k].y, dd1 = av[k].y * bn + an * bv[k].y;
      float n2 = av[k].z * bn - an * bv[k].z, dd2 = av[k].z * bn + an * bv[k].z;
      float n3 = av[k].w * bn - an * bv[k].w, dd3 = av[k].w * bn + an * bv[k].w;
      num2 += n0 * n0 + n1 * n1 + n2 * n2 + n3 * n3;
      den2 += dd0 * dd0 + dd1 * dd1 + dd2 * dd2 + dd3 * dd3;
    }
    ang = 2.0f * atan2f(sqrtf(num2), sqrtf(den2));
  }

  // Wave sum of the 31 angles -> p_curv everywhere.
  float tot = ang;
  #pragma unroll
  for (int m = 1; m < 64; m <<= 1) tot += __shfl_xor(tot, m, 64);
  float p_curv = tot / 31.0f;

  // Outputs (flat concatenation, all as float32).
  float* out_xyz  = out;                              // 8192*3
  float* out_feat = out + (size_t)BATCH * NGROUP * 3; // 8192*33
  float* out_sw   = out_feat + (size_t)BATCH * NGROUP * (FDIM + 1);
  float* out_lab  = out_sw  + (size_t)BATCH * NGROUP;
  float* out_sif  = out_lab + (size_t)BATCH * NGROUP;

  if (lane < FDIM)  out_feat[(size_t)qid * (FDIM + 1) + lane] = my_a;
  if (lane == FDIM) out_feat[(size_t)qid * (FDIM + 1) + FDIM] = p_curv;
  if (lane == 0) {
    out_xyz[(size_t)qid * 3 + 0] = qx;
    out_xyz[(size_t)qid * 3 + 1] = qy;
    out_xyz[(size_t)qid * 3 + 2] = qz;
    out_sw[qid]  = (p_curv > 0.087266f) ? 1.0f : 0.0f;
    out_lab[qid] = (float)labels[gq];
    out_sif[qid] = (float)gq;   // s_idx + b*N
  }
}

extern "C" void kernel_launch(void* const* d_in, const int* in_sizes, int n_in,
                              void* d_out, int out_size, void* d_ws, size_t ws_size,
                              hipStream_t stream) {
  const float* coord  = (const float*)d_in[0];
  const float* feat   = (const float*)d_in[1];
  const int*   labels = (const int*)d_in[2];

  // ws layout: [2][8][64] u64 ping-pong slots (zeroed), then 8*1024 int s_idx.
  unsigned long long* slots = (unsigned long long*)d_ws;
  int* s_idx_ws = (int*)((char*)d_ws +
                         2 * BATCH * WSLOTS * sizeof(unsigned long long));

  hipMemsetAsync(d_ws, 0, 2 * BATCH * WSLOTS * sizeof(unsigned long long),
                 stream);
  fps_kernel<<<BATCH * NBLK, FTPB, 0, stream>>>(coord, slots, s_idx_ws);
  knn_kernel<<<(BATCH * NGROUP) / 4, 256, 0, stream>>>(coord, feat, labels,
                                                       s_idx_ws, (float*)d_out);
}

// Round 9
// 3351.193 us; speedup vs baseline: 3.8471x; 3.8471x over previous
//
#include <hip/hip_runtime.h>
#include <math.h>

#define BATCH   8
#define NPTS    32768
#define FDIM    32
#define NGROUP  1024
#define GSIZE   32
#define KLANE   8       // per-lane candidate list length in KNN

// Multi-block FPS: 8 blocks/batch x 512 thr x 8 pts/thr = 32768.
#define NBLK    8
#define FTPB    512
#define CHUNK   (NPTS / NBLK)   // 4096 points per block

// Exact float32 distance in the reference's association: ((dx^2+dy^2)+dz^2),
// contraction blocked so bits match the numpy ref (argmax stability).
__device__ __forceinline__ float dist2f(float ax, float ay, float az,
                                        float bx, float by, float bz) {
  float dx = __fsub_rn(ax, bx);
  float dy = __fsub_rn(ay, by);
  float dz = __fsub_rn(az, bz);
  return __fadd_rn(__fadd_rn(__fmul_rn(dx, dx), __fmul_rn(dy, dy)),
                   __fmul_rn(dz, dz));
}

#define X8(M) M(0) M(1) M(2) M(3) M(4) M(5) M(6) M(7)

// ---------------------------------------------------------------------------
// Kernel A: FPS. R6 topology (8 blocks/batch, one batch per XCD, ONE 64B
// global slot line per batch, 8 writers) + R7-style tag-spin detection
// (no s_barrier in the loop, no LDS bcast, no two-level reduce):
//   wave argmax -> LDS-publish tagged candidate (replaces barrier B1)
//   wid0: LDS tag-spin over 8 slots -> block max -> global relaxed store
//   ALL waves: poll the batch's 8 global slots (one line) until all tag==t,
//   8-wide in-register max -> global argmax; start c3[gp] + update at once.
// R7's failure mode (512 waves x 8 lines x 64 writers) is avoided: 8
// writers, one line, 64 polling waves per batch.
// Packing: tag<<47 | dist_bits<<15 | (0x7FFF-idx)  -> u64 max == argmax
// with numpy lowest-index tie-break. Parity ping-pong (t&1) at BOTH levels:
// a publisher reaches tag t+2 only after every poller exited round t (its
// t+1 publish is gated on their t+1/t publications), so same-parity
// clobbering of a still-needed value is impossible. One __syncthreads
// before the loop: LDS tags must be initialized before anyone spins.
// ---------------------------------------------------------------------------
__global__ __launch_bounds__(FTPB) void fps_kernel(
    const float* __restrict__ coord,
    unsigned long long* __restrict__ slots,   // [2][BATCH][8], pre-zeroed
    int* __restrict__ s_idx_out) {
  __shared__ unsigned long long lred[2][NBLK];   // [parity][wid]

  const int gb   = blockIdx.x;        // 0..63
  const int b    = gb & 7;            // batch (XCD-local under %8 mapping)
  const int bk   = gb >> 3;           // block within batch
  const int tid  = threadIdx.x;
  const int lane = tid & 63;
  const int wid  = tid >> 6;          // 0..7
  const float* __restrict__ c = coord + (size_t)b * NPTS * 3;
  const float3* __restrict__ c3 = (const float3*)c;

  const int pbase = bk * CHUNK + tid; // + i*FTPB

#define DECL8(i) float x##i, y##i, z##i, d##i;
  X8(DECL8)
#undef DECL8

  // Init LDS tag slots (t starts at 1; 0-tag == "not published").
  if (tid < 2 * NBLK) ((unsigned long long*)lred)[tid] = 0ULL;

  // Load owned points, distance to batch point 0, local argmax
  // (ascending point index + strict > == np.argmax lowest-index tie-break).
  float qx = c[0], qy = c[1], qz = c[2];
  float bestv = -1.0f; int bestp = 0;
#define LOAD8(i) { int p = pbase + (i) * FTPB; float3 v = c3[p];            \
    x##i = v.x; y##i = v.y; z##i = v.z;                                      \
    float t2 = dist2f(v.x, v.y, v.z, qx, qy, qz); d##i = t2;                 \
    if (t2 > bestv) { bestv = t2; bestp = p; } }
  X8(LOAD8)
#undef LOAD8

  if (gb == 0 || (bk == 0 && lane == 0 && wid == 0))
    if (bk == 0 && wid == 0 && lane == 0) s_idx_out[b * NGROUP + 0] = 0;

  __syncthreads();   // only barrier: LDS tag init must precede any spin

  for (int t = 1; t < NGROUP; ++t) {
    // Wave argmax over this wave's 512 points (max value, tie -> min index).
    float v = bestv; int p = bestp;
    #pragma unroll
    for (int m = 1; m < 64; m <<= 1) {
      float ov = __shfl_xor(v, m, 64);
      int   op = __shfl_xor(p, m, 64);
      if (ov > v || (ov == v && op < p)) { v = ov; p = op; }
    }
    const unsigned long long pk =
        ((unsigned long long)t << 47)
      | ((unsigned long long)__float_as_uint(v) << 15)
      | (unsigned long long)(0x7FFF - p);

    // Publish to this block's LDS slot (replaces barrier B1).
    if (lane == 0)
      __hip_atomic_store(&lred[t & 1][wid], pk, __ATOMIC_RELAXED,
                         __HIP_MEMORY_SCOPE_WORKGROUP);

    unsigned long long* gbase =
        slots + (size_t)(t & 1) * (BATCH * NBLK) + (b << 3);

    // wid0: LDS tag-spin -> block max -> global publish.
    if (wid == 0) {
      unsigned long long lv;
      do {
        lv = __hip_atomic_load(&lred[t & 1][lane & 7], __ATOMIC_RELAXED,
                               __HIP_MEMORY_SCOPE_WORKGROUP);
      } while (__ballot((int)(lv >> 47) == t) != ~0ULL);
      #pragma unroll
      for (int m = 1; m < 8; m <<= 1) {
        unsigned long long o = __shfl_xor(lv, m, 64);
        if (o > lv) lv = o;
      }
      if (lane == 0)
        __hip_atomic_store(gbase + bk, lv, __ATOMIC_RELAXED,
                           __HIP_MEMORY_SCOPE_AGENT);
    }

    // All waves: poll the batch's 8 global slots (one cache line).
    unsigned long long gv;
    do {
      gv = __hip_atomic_load(gbase + (lane & 7), __ATOMIC_RELAXED,
                             __HIP_MEMORY_SCOPE_AGENT);
    } while (__ballot((int)(gv >> 47) == t) != ~0ULL);
    #pragma unroll
    for (int m = 1; m < 8; m <<= 1) {
      unsigned long long o = __shfl_xor(gv, m, 64);
      if (o > gv) gv = o;
    }
    const int gp = 0x7FFF - (int)(gv & 0x7FFF);
    if (bk == 0 && wid == 0 && lane == 0) s_idx_out[b * NGROUP + t] = gp;
    if (t == NGROUP - 1) break;

    // Fetch winner coords (uniform wave load, L2-resident) + update dists.
    float3 q = c3[gp];
    qx = q.x; qy = q.y; qz = q.z;
    bestv = -1.0f; bestp = 0;
#define UPD8(i) { float t2 = dist2f(x##i, y##i, z##i, qx, qy, qz);           \
    float nd = fminf(d##i, t2); d##i = nd;                                   \
    if (nd > bestv) { bestv = nd; bestp = pbase + (i) * FTPB; } }
    X8(UPD8)
#undef UPD8
  }
}

// ---------------------------------------------------------------------------
// Kernel B: one wave per sampled point. Brute-force 32-NN (per-lane sorted
// top-8 over its 512 strided points, then 32 wave-argmin extractions),
// then the feature-angle curvature and all 5 outputs.
// ---------------------------------------------------------------------------
__global__ __launch_bounds__(256) void knn_kernel(
    const float* __restrict__ coord, const float* __restrict__ feat,
    const int* __restrict__ labels, const int* __restrict__ s_idx_ws,
    float* __restrict__ out) {
  const int lane = threadIdx.x & 63;
  const int qid  = (blockIdx.x << 2) + (threadIdx.x >> 6);  // 0..8191
  const int b    = qid >> 10;
  const float* __restrict__ c = coord + (size_t)b * NPTS * 3;

  int sp = __builtin_amdgcn_readfirstlane(s_idx_ws[qid]);
  const int gq = b * NPTS + sp;
  const float qx = coord[(size_t)gq * 3 + 0];
  const float qy = coord[(size_t)gq * 3 + 1];
  const float qz = coord[(size_t)gq * 3 + 2];

  // Per-lane ascending top-8 (value, index), static indexing only.
  float lv[KLANE]; int li[KLANE];
  #pragma unroll
  for (int j = 0; j < KLANE; ++j) { lv[j] = 1e30f; li[j] = 0x7fffffff; }

  for (int s = 0; s < NPTS / 64; ++s) {
    int p = (s << 6) + lane;
    float3 v = ((const float3*)c)[p];
    float d2 = dist2f(v.x, v.y, v.z, qx, qy, qz);
    if (d2 < lv[KLANE - 1]) {
      // Branchless unrolled sorted insert; strict < keeps equal-distance
      // earlier (lower) indices first, matching lax.top_k tie order.
      #pragma unroll
      for (int j = KLANE - 1; j >= 1; --j) {
        bool up = d2 < lv[j - 1];
        float nv = up ? lv[j - 1] : ((d2 < lv[j]) ? d2 : lv[j]);
        int   ni = up ? li[j - 1] : ((d2 < lv[j]) ? p  : li[j]);
        lv[j] = nv; li[j] = ni;
      }
      if (d2 < lv[0]) { lv[0] = d2; li[0] = p; }
    }
  }

  // Extract the 32 globally smallest (ascending, tie -> lower index).
  // Round 0 is the query itself (d2 == 0), excluded from the angle mean
  // like angles[:, :, 1:].
  int nbp = 0;
  for (int r = 0; r < GSIZE; ++r) {
    float mv = lv[0]; int mp = li[0];
    #pragma unroll
    for (int m = 1; m < 64; m <<= 1) {
      float ov = __shfl_xor(mv, m, 64);
      int   op = __shfl_xor(mp, m, 64);
      if (ov < mv || (ov == mv && op < mp)) { mv = ov; mp = op; }
    }
    if (lane == r) nbp = mp;
    if (lv[0] == mv && li[0] == mp) {  // unique winner pops its head
      #pragma unroll
      for (int j = 0; j < KLANE - 1; ++j) { lv[j] = lv[j + 1]; li[j] = li[j + 1]; }
      lv[KLANE - 1] = 1e30f; li[KLANE - 1] = 0x7fffffff;
    }
  }

  // Angle for lanes 1..31: theta = 2*atan2(||a*|b| - |a|*b||, ||a*|b| + |a|*b||)
  const float* aRow = feat + (size_t)gq * FDIM;
  float my_a = (lane < FDIM) ? aRow[lane] : 0.0f;

  float ang = 0.0f;
  if (lane >= 1 && lane < GSIZE) {
    const float4* a4 = (const float4*)aRow;
    const float4* b4 = (const float4*)(feat + ((size_t)b * NPTS + nbp) * FDIM);
    float4 av[FDIM / 4], bv[FDIM / 4];
    float aa = 0.0f, bb = 0.0f;
    #pragma unroll
    for (int k = 0; k < FDIM / 4; ++k) {
      av[k] = a4[k]; bv[k] = b4[k];
      aa += av[k].x * av[k].x + av[k].y * av[k].y + av[k].z * av[k].z + av[k].w * av[k].w;
      bb += bv[k].x * bv[k].x + bv[k].y * bv[k].y + bv[k].z * bv[k].z + bv[k].w * bv[k].w;
    }
    float an = sqrtf(aa), bn = sqrtf(bb);
    float num2 = 0.0f, den2 = 0.0f;
    #pragma unroll
    for (int k = 0; k < FDIM / 4; ++k) {
      float n0 = av[k].x * bn - an * bv[k].x, dd0 = av[k].x * bn + an * bv[k].x;
      float n1 = av[k].y * bn - an * bv[k].y, dd1 = av[k].y * bn + an * bv[k].y;
      float n2 = av[k].z * bn - an * bv[k].z, dd2 = av[k].z * bn + an * bv[k].z;
      float n3 = av[k].w * bn - an * bv[k].w, dd3 = av[k].w * bn + an * bv[k].w;
      num2 += n0 * n0 + n1 * n1 + n2 * n2 + n3 * n3;
      den2 += dd0 * dd0 + dd1 * dd1 + dd2 * dd2 + dd3 * dd3;
    }
    ang = 2.0f * atan2f(sqrtf(num2), sqrtf(den2));
  }

  // Wave sum of the 31 angles -> p_curv everywhere.
  float tot = ang;
  #pragma unroll
  for (int m = 1; m < 64; m <<= 1) tot += __shfl_xor(tot, m, 64);
  float p_curv = tot / 31.0f;

  // Outputs (flat concatenation, all as float32).
  float* out_xyz  = out;                              // 8192*3
  float* out_feat = out + (size_t)BATCH * NGROUP * 3; // 8192*33
  float* out_sw   = out_feat + (size_t)BATCH * NGROUP * (FDIM + 1);
  float* out_lab  = out_sw  + (size_t)BATCH * NGROUP;
  float* out_sif  = out_lab + (size_t)BATCH * NGROUP;

  if (lane < FDIM)  out_feat[(size_t)qid * (FDIM + 1) + lane] = my_a;
  if (lane == FDIM) out_feat[(size_t)qid * (FDIM + 1) + FDIM] = p_curv;
  if (lane == 0) {
    out_xyz[(size_t)qid * 3 + 0] = qx;
    out_xyz[(size_t)qid * 3 + 1] = qy;
    out_xyz[(size_t)qid * 3 + 2] = qz;
    out_sw[qid]  = (p_curv > 0.087266f) ? 1.0f : 0.0f;
    out_lab[qid] = (float)labels[gq];
    out_sif[qid] = (float)gq;   // s_idx + b*N
  }
}

extern "C" void kernel_launch(void* const* d_in, const int* in_sizes, int n_in,
                              void* d_out, int out_size, void* d_ws, size_t ws_size,
                              hipStream_t stream) {
  const float* coord  = (const float*)d_in[0];
  const float* feat   = (const float*)d_in[1];
  const int*   labels = (const int*)d_in[2];

  // ws layout: [2][8][8] u64 ping-pong slots (zeroed), then 8*1024 int s_idx.
  unsigned long long* slots = (unsigned long long*)d_ws;
  int* s_idx_ws = (int*)((char*)d_ws +
                         2 * BATCH * NBLK * sizeof(unsigned long long));

  hipMemsetAsync(d_ws, 0, 2 * BATCH * NBLK * sizeof(unsigned long long),
                 stream);
  fps_kernel<<<BATCH * NBLK, FTPB, 0, stream>>>(coord, slots, s_idx_ws);
  knn_kernel<<<(BATCH * NGROUP) / 4, 256, 0, stream>>>(coord, feat, labels,
                                                       s_idx_ws, (float*)d_out);
}

// Round 10
// 3134.055 us; speedup vs baseline: 4.1136x; 1.0693x over previous
//
#include <hip/hip_runtime.h>
#include <math.h>

#define BATCH   8
#define NPTS    32768
#define FDIM    32
#define NGROUP  1024
#define GSIZE   32
#define KLANE   8       // per-lane candidate list length in KNN

// Multi-block FPS config: 8 blocks/batch x 512 thr x 8 pts/thr = 32768.
#define NBLK    8
#define FTPB    512
#define CHUNK   (NPTS / NBLK)   // 4096 points per block

// Exact float32 distance in the reference's association: ((dx^2+dy^2)+dz^2),
// contraction blocked so bits match the numpy ref (argmax stability).
__device__ __forceinline__ float dist2f(float ax, float ay, float az,
                                        float bx, float by, float bz) {
  float dx = __fsub_rn(ax, bx);
  float dy = __fsub_rn(ay, by);
  float dz = __fsub_rn(az, bz);
  return __fadd_rn(__fadd_rn(__fmul_rn(dx, dx), __fmul_rn(dy, dy)),
                   __fmul_rn(dz, dz));
}

#define X8(M) M(0) M(1) M(2) M(3) M(4) M(5) M(6) M(7)

// ---------------------------------------------------------------------------
// Kernel A: FPS, R6 structure verbatim (best measured: 2645 us).
// R6/R7/R8 post-mortems: consensus latency (~2.1k+ cyc store->observe +
// stragglers, likely at reduced DPM clock) dominates and is invariant to
// handshake structure; this is the accepted floor for this topology.
// 8 blocks/batch (batch = gb&7 -> one batch per XCD under %8 round-robin),
// packed-candidate publish + poll, parity ping-pong slots.
// ---------------------------------------------------------------------------
__global__ __launch_bounds__(FTPB) void fps_kernel(
    const float* __restrict__ coord,
    unsigned long long* __restrict__ slots,   // [2][BATCH*NBLK], pre-zeroed
    int* __restrict__ s_idx_out) {
  const int gb   = blockIdx.x;        // 0..63
  const int b    = gb & 7;            // batch  (== XCD id under %8 mapping)
  const int bk   = gb >> 3;           // block within batch
  const int tid  = threadIdx.x;
  const int lane = tid & 63;
  const int wid  = tid >> 6;          // 0..7
  const float* __restrict__ c = coord + (size_t)b * NPTS * 3;
  const float3* __restrict__ c3 = (const float3*)c;

  __shared__ float redv[8];
  __shared__ int   redp[8];
  __shared__ unsigned long long bcast;

  const int pbase = bk * CHUNK + tid; // + i*FTPB

#define DECL8(i) float x##i, y##i, z##i, d##i;
  X8(DECL8)
#undef DECL8

  // Init: load owned points, distance to batch point 0, local argmax
  // (ascending point index + strict > == np.argmax lowest-index tie-break).
  float qx = c[0], qy = c[1], qz = c[2];
  float bestv = -1.0f; int bestp = 0;
#define LOAD8(i) { int p = pbase + (i) * FTPB; float3 v = c3[p];            \
    x##i = v.x; y##i = v.y; z##i = v.z;                                      \
    float t2 = dist2f(v.x, v.y, v.z, qx, qy, qz); d##i = t2;                 \
    if (t2 > bestv) { bestv = t2; bestp = p; } }
  X8(LOAD8)
#undef LOAD8

  if (bk == 0 && tid == 0) s_idx_out[b * NGROUP + 0] = 0;

  for (int t = 1; t < NGROUP; ++t) {
    // Wave-level argmax (max value, tie -> min index).
    float v = bestv; int p = bestp;
    #pragma unroll
    for (int m = 1; m < 64; m <<= 1) {
      float ov = __shfl_xor(v, m, 64);
      int   op = __shfl_xor(p, m, 64);
      if (ov > v || (ov == v && op < p)) { v = ov; p = op; }
    }
    if (lane == 0) { redv[wid] = v; redp[wid] = p; }
    __syncthreads();   // B1

    if (wid == 0) {
      // Block-level argmax over the 8 wave candidates (replicated butterfly).
      float gv = redv[lane & 7]; int gp = redp[lane & 7];
      #pragma unroll
      for (int m = 1; m < 8; m <<= 1) {
        float ov = __shfl_xor(gv, m, 64);
        int   op = __shfl_xor(gp, m, 64);
        if (ov > gv || (ov == gv && op < gp)) { gv = ov; gp = op; }
      }
      unsigned long long* base = slots + (size_t)(t & 1) * (BATCH * NBLK);
      if (lane == 0) {
        unsigned long long pk = ((unsigned long long)t << 47)
                              | ((unsigned long long)__float_as_uint(gv) << 15)
                              | (unsigned long long)(0x7FFF - gp);
        __hip_atomic_store(base + (b << 3) + bk, pk, __ATOMIC_RELEASE,
                           __HIP_MEMORY_SCOPE_AGENT);
      }
      // Poll: lanes 0..7 each watch one slot of this batch until tag == t.
      unsigned long long pk2 = 0;
      if (lane < 8) {
        const unsigned long long* sl = base + (b << 3) + lane;
        do {
          pk2 = __hip_atomic_load(sl, __ATOMIC_ACQUIRE,
                                  __HIP_MEMORY_SCOPE_AGENT);
        } while ((int)(pk2 >> 47) != t);
      }
      #pragma unroll
      for (int m = 1; m < 8; m <<= 1) {
        unsigned long long o = __shfl_xor(pk2, m, 64);
        if (o > pk2) pk2 = o;
      }
      if (lane == 0) bcast = pk2;
    }
    __syncthreads();   // B2

    const unsigned long long wpk = bcast;
    const int gp = 0x7FFF - (int)(wpk & 0x7FFF);
    if (bk == 0 && tid == 0) s_idx_out[b * NGROUP + t] = gp;
    if (t == NGROUP - 1) break;

    // Fetch winner coords (same-address wave load, L1/L2-resident) + update.
    float3 q = c3[gp];
    qx = q.x; qy = q.y; qz = q.z;
    bestv = -1.0f; bestp = 0;
#define UPD8(i) { float t2 = dist2f(x##i, y##i, z##i, qx, qy, qz);           \
    float nd = fminf(d##i, t2); d##i = nd;                                   \
    if (nd > bestv) { bestv = nd; bestp = pbase + (i) * FTPB; } }
    X8(UPD8)
#undef UPD8
  }
}

// ---------------------------------------------------------------------------
// Kernel B: one wave per sampled point. Brute-force 32-NN, then the
// feature-angle curvature and all 5 outputs.
// R9: scan restructured to 4 points per lane via 3 float4 loads (wave reads
// 3 contiguous KB -> fully coalesced dwordx4), 128 outer iterations instead
// of 512 -> 4x fewer load instructions, 4 independent insert candidates per
// body for latency hiding. Tie semantics unchanged: ascending index
// processing + explicit (val,idx) compare in extraction.
// ---------------------------------------------------------------------------
__global__ __launch_bounds__(256) void knn_kernel(
    const float* __restrict__ coord, const float* __restrict__ feat,
    const int* __restrict__ labels, const int* __restrict__ s_idx_ws,
    float* __restrict__ out) {
  const int lane = threadIdx.x & 63;
  const int qid  = (blockIdx.x << 2) + (threadIdx.x >> 6);  // 0..8191
  const int b    = qid >> 10;
  const float* __restrict__ c = coord + (size_t)b * NPTS * 3;

  int sp = __builtin_amdgcn_readfirstlane(s_idx_ws[qid]);
  const int gq = b * NPTS + sp;
  const float qx = coord[(size_t)gq * 3 + 0];
  const float qy = coord[(size_t)gq * 3 + 1];
  const float qz = coord[(size_t)gq * 3 + 2];

  // Per-lane ascending top-8 (value, index), static indexing only.
  float lv[KLANE]; int li[KLANE];
  #pragma unroll
  for (int j = 0; j < KLANE; ++j) { lv[j] = 1e30f; li[j] = 0x7fffffff; }

  // Branchless sorted insert; strict < keeps equal-distance earlier (lower)
  // indices first, matching lax.top_k tie order.
#define INSERT(D2, P) \
  if ((D2) < lv[KLANE - 1]) { \
    _Pragma("unroll") \
    for (int j = KLANE - 1; j >= 1; --j) { \
      bool up = (D2) < lv[j - 1]; \
      float nv = up ? lv[j - 1] : (((D2) < lv[j]) ? (D2) : lv[j]); \
      int   ni = up ? li[j - 1] : (((D2) < lv[j]) ? (P)  : li[j]); \
      lv[j] = nv; li[j] = ni; \
    } \
    if ((D2) < lv[0]) { lv[0] = (D2); li[0] = (P); } \
  }

  for (int s = 0; s < NPTS / 256; ++s) {   // 128 iterations, 4 pts/lane
    int p = (s << 8) | (lane << 2);
    const float4* c4 = (const float4*)(c + (size_t)p * 3);
    float4 f0 = c4[0], f1 = c4[1], f2 = c4[2];
    float dA = dist2f(f0.x, f0.y, f0.z, qx, qy, qz);
    float dB = dist2f(f0.w, f1.x, f1.y, qx, qy, qz);
    float dC = dist2f(f1.z, f1.w, f2.x, qx, qy, qz);
    float dD = dist2f(f2.y, f2.z, f2.w, qx, qy, qz);
    INSERT(dA, p);
    INSERT(dB, p + 1);
    INSERT(dC, p + 2);
    INSERT(dD, p + 3);
  }
#undef INSERT

  // Extract the 32 globally smallest (ascending, tie -> lower index).
  // Round 0 is the query itself (d2 == 0), excluded from the angle mean
  // like angles[:, :, 1:].
  int nbp = 0;
  for (int r = 0; r < GSIZE; ++r) {
    float mv = lv[0]; int mp = li[0];
    #pragma unroll
    for (int m = 1; m < 64; m <<= 1) {
      float ov = __shfl_xor(mv, m, 64);
      int   op = __shfl_xor(mp, m, 64);
      if (ov < mv || (ov == mv && op < mp)) { mv = ov; mp = op; }
    }
    if (lane == r) nbp = mp;
    if (lv[0] == mv && li[0] == mp) {  // unique winner pops its head
      #pragma unroll
      for (int j = 0; j < KLANE - 1; ++j) { lv[j] = lv[j + 1]; li[j] = li[j + 1]; }
      lv[KLANE - 1] = 1e30f; li[KLANE - 1] = 0x7fffffff;
    }
  }

  // Angle for lanes 1..31: theta = 2*atan2(||a*|b| - |a|*b||, ||a*|b| + |a|*b||)
  const float* aRow = feat + (size_t)gq * FDIM;
  float my_a = (lane < FDIM) ? aRow[lane] : 0.0f;

  float ang = 0.0f;
  if (lane >= 1 && lane < GSIZE) {
    const float4* a4 = (const float4*)aRow;
    const float4* b4 = (const float4*)(feat + ((size_t)b * NPTS + nbp) * FDIM);
    float4 av[FDIM / 4], bv[FDIM / 4];
    float aa = 0.0f, bb = 0.0f;
    #pragma unroll
    for (int k = 0; k < FDIM / 4; ++k) {
      av[k] = a4[k]; bv[k] = b4[k];
      aa += av[k].x * av[k].x + av[k].y * av[k].y + av[k].z * av[k].z + av[k].w * av[k].w;
      bb += bv[k].x * bv[k].x + bv[k].y * bv[k].y + bv[k].z * bv[k].z + bv[k].w * bv[k].w;
    }
    float an = sqrtf(aa), bn = sqrtf(bb);
    float num2 = 0.0f, den2 = 0.0f;
    #pragma unroll
    for (int k = 0; k < FDIM / 4; ++k) {
      float n0 = av[k].x * bn - an * bv[k].x, dd0 = av[k].x * bn + an * bv[k].x;
      float n1 = av[k].y * bn - an * bv[k].y, dd1 = av[k].y * bn + an * bv[k].y;
      float n2 = av[k].z * bn - an * bv[k].z, dd2 = av[k].z * bn + an * bv[k].z;
      float n3 = av[k].w * bn - an * bv[k].w, dd3 = av[k].w * bn + an * bv[k].w;
      num2 += n0 * n0 + n1 * n1 + n2 * n2 + n3 * n3;
      den2 += dd0 * dd0 + dd1 * dd1 + dd2 * dd2 + dd3 * dd3;
    }
    ang = 2.0f * atan2f(sqrtf(num2), sqrtf(den2));
  }

  // Wave sum of the 31 angles -> p_curv everywhere.
  float tot = ang;
  #pragma unroll
  for (int m = 1; m < 64; m <<= 1) tot += __shfl_xor(tot, m, 64);
  float p_curv = tot / 31.0f;

  // Outputs (flat concatenation, all as float32).
  float* out_xyz  = out;                              // 8192*3
  float* out_feat = out + (size_t)BATCH * NGROUP * 3; // 8192*33
  float* out_sw   = out_feat + (size_t)BATCH * NGROUP * (FDIM + 1);
  float* out_lab  = out_sw  + (size_t)BATCH * NGROUP;
  float* out_sif  = out_lab + (size_t)BATCH * NGROUP;

  if (lane < FDIM)  out_feat[(size_t)qid * (FDIM + 1) + lane] = my_a;
  if (lane == FDIM) out_feat[(size_t)qid * (FDIM + 1) + FDIM] = p_curv;
  if (lane == 0) {
    out_xyz[(size_t)qid * 3 + 0] = qx;
    out_xyz[(size_t)qid * 3 + 1] = qy;
    out_xyz[(size_t)qid * 3 + 2] = qz;
    out_sw[qid]  = (p_curv > 0.087266f) ? 1.0f : 0.0f;
    out_lab[qid] = (float)labels[gq];
    out_sif[qid] = (float)gq;   // s_idx + b*N
  }
}

extern "C" void kernel_launch(void* const* d_in, const int* in_sizes, int n_in,
                              void* d_out, int out_size, void* d_ws, size_t ws_size,
                              hipStream_t stream) {
  const float* coord  = (const float*)d_in[0];
  const float* feat   = (const float*)d_in[1];
  const int*   labels = (const int*)d_in[2];

  // ws layout: [2][64] u64 ping-pong slots (zeroed), then 8*1024 int s_idx.
  unsigned long long* slots = (unsigned long long*)d_ws;
  int* s_idx_ws = (int*)((char*)d_ws + 2 * BATCH * NBLK * sizeof(unsigned long long));

  hipMemsetAsync(d_ws, 0, 2 * BATCH * NBLK * sizeof(unsigned long long), stream);
  fps_kernel<<<BATCH * NBLK, FTPB, 0, stream>>>(coord, slots, s_idx_ws);
  knn_kernel<<<(BATCH * NGROUP) / 4, 256, 0, stream>>>(coord, feat, labels,
                                                       s_idx_ws, (float*)d_out);
}

// Round 11
// 2928.411 us; speedup vs baseline: 4.4025x; 1.0702x over previous
//
#include <hip/hip_runtime.h>
#include <math.h>

#define BATCH   8
#define NPTS    32768
#define FDIM    32
#define NGROUP  1024
#define GSIZE   32
#define KLANE   8       // per-lane candidate list length in KNN

// FPS: 8 blocks/batch x 512 thr x 8 pts/thr = 32768.
#define NBLK    8
#define FTPB    512
#define CHUNK   (NPTS / NBLK)     // 4096 points per block
#define NFPSBLK (BATCH * NBLK)    // 64 producer blocks (first in grid)
#define KNNQPB  8                 // 8 queries (waves) per 512-thr knn block
#define NKNNBLK ((BATCH * NGROUP) / KNNQPB)   // 1024 consumer blocks

// Exact float32 distance in the reference's association: ((dx^2+dy^2)+dz^2),
// contraction blocked so bits match the numpy ref (argmax stability).
__device__ __forceinline__ float dist2f(float ax, float ay, float az,
                                        float bx, float by, float bz) {
  float dx = __fsub_rn(ax, bx);
  float dy = __fsub_rn(ay, by);
  float dz = __fsub_rn(az, bz);
  return __fadd_rn(__fadd_rn(__fmul_rn(dx, dx), __fmul_rn(dy, dy)),
                   __fmul_rn(dz, dz));
}

#define X8(M) M(0) M(1) M(2) M(3) M(4) M(5) M(6) M(7)

// ---------------------------------------------------------------------------
// Fused producer-consumer kernel.
// Blocks 0..63: FPS, R6 structure verbatim (best measured: 2645 us; the
//   consensus chain is latency-floor-bound and invariant to handshake
//   structure per R6/R7/R8). Publishes s_idx as (idx+1) via agent-scope
//   relaxed atomic stores (0 == not yet published; ws pre-zeroed).
// Blocks 64..1087: KNN, one wave per sampled point; spin on s_idx_ws[qid]
//   until nonzero (relaxed suffices: the index IS the payload, and the
//   dependent loads hit read-only inputs), s_sleep backoff, then the R9
//   float4 scan + curvature + outputs.
// Deadlock-free: producers occupy the lowest block IDs -> dispatched first;
// consumers only read. Consumer dispatch order ~matches publication order
// (low t first), so early consumers drain fast and free CU slots.
// Overlap hides nearly all of knn's ~480 us inside the fps window.
// ---------------------------------------------------------------------------
__global__ __launch_bounds__(FTPB) void fused_kernel(
    const float* __restrict__ coord, const float* __restrict__ feat,
    const int* __restrict__ labels,
    unsigned long long* __restrict__ slots,   // [2][64] u64, pre-zeroed
    int* __restrict__ s_idx_ws,               // [8192] idx+1, pre-zeroed
    float* __restrict__ out) {
  __shared__ float redv[8];
  __shared__ int   redp[8];
  __shared__ unsigned long long bcast;

  const int bx   = blockIdx.x;
  const int tid  = threadIdx.x;
  const int lane = tid & 63;
  const int wid  = tid >> 6;          // 0..7

  if (bx < NFPSBLK) {
    // ===================== FPS (producer) =====================
    const int gb   = bx;
    const int b    = gb & 7;          // batch (XCD-local under %8 mapping)
    const int bk   = gb >> 3;         // block within batch
    const float* __restrict__ c = coord + (size_t)b * NPTS * 3;
    const float3* __restrict__ c3 = (const float3*)c;
    const int pbase = bk * CHUNK + tid;

#define DECL8(i) float x##i, y##i, z##i, d##i;
    X8(DECL8)
#undef DECL8

    // Init: distance to batch point 0; local argmax (ascending index +
    // strict > == np.argmax lowest-index tie-break).
    float qx = c[0], qy = c[1], qz = c[2];
    float bestv = -1.0f; int bestp = 0;
#define LOAD8(i) { int p = pbase + (i) * FTPB; float3 v = c3[p];            \
    x##i = v.x; y##i = v.y; z##i = v.z;                                      \
    float t2 = dist2f(v.x, v.y, v.z, qx, qy, qz); d##i = t2;                 \
    if (t2 > bestv) { bestv = t2; bestp = p; } }
    X8(LOAD8)
#undef LOAD8

    if (bk == 0 && tid == 0)
      __hip_atomic_store(&s_idx_ws[b * NGROUP + 0], 1, __ATOMIC_RELAXED,
                         __HIP_MEMORY_SCOPE_AGENT);   // idx 0, +1 encoding

    for (int t = 1; t < NGROUP; ++t) {
      // Wave-level argmax (max value, tie -> min index).
      float v = bestv; int p = bestp;
      #pragma unroll
      for (int m = 1; m < 64; m <<= 1) {
        float ov = __shfl_xor(v, m, 64);
        int   op = __shfl_xor(p, m, 64);
        if (ov > v || (ov == v && op < p)) { v = ov; p = op; }
      }
      if (lane == 0) { redv[wid] = v; redp[wid] = p; }
      __syncthreads();   // B1

      if (wid == 0) {
        float gv = redv[lane & 7]; int gp = redp[lane & 7];
        #pragma unroll
        for (int m = 1; m < 8; m <<= 1) {
          float ov = __shfl_xor(gv, m, 64);
          int   op = __shfl_xor(gp, m, 64);
          if (ov > gv || (ov == gv && op < gp)) { gv = ov; gp = op; }
        }
        unsigned long long* base = slots + (size_t)(t & 1) * (BATCH * NBLK);
        if (lane == 0) {
          unsigned long long pk = ((unsigned long long)t << 47)
                                | ((unsigned long long)__float_as_uint(gv) << 15)
                                | (unsigned long long)(0x7FFF - gp);
          __hip_atomic_store(base + (b << 3) + bk, pk, __ATOMIC_RELEASE,
                             __HIP_MEMORY_SCOPE_AGENT);
        }
        unsigned long long pk2 = 0;
        if (lane < 8) {
          const unsigned long long* sl = base + (b << 3) + lane;
          do {
            pk2 = __hip_atomic_load(sl, __ATOMIC_ACQUIRE,
                                    __HIP_MEMORY_SCOPE_AGENT);
          } while ((int)(pk2 >> 47) != t);
        }
        #pragma unroll
        for (int m = 1; m < 8; m <<= 1) {
          unsigned long long o = __shfl_xor(pk2, m, 64);
          if (o > pk2) pk2 = o;
        }
        if (lane == 0) bcast = pk2;
      }
      __syncthreads();   // B2

      const unsigned long long wpk = bcast;
      const int gp = 0x7FFF - (int)(wpk & 0x7FFF);
      if (bk == 0 && tid == 0)
        __hip_atomic_store(&s_idx_ws[b * NGROUP + t], gp + 1,
                           __ATOMIC_RELAXED, __HIP_MEMORY_SCOPE_AGENT);
      if (t == NGROUP - 1) break;

      float3 q = c3[gp];
      qx = q.x; qy = q.y; qz = q.z;
      bestv = -1.0f; bestp = 0;
#define UPD8(i) { float t2 = dist2f(x##i, y##i, z##i, qx, qy, qz);           \
    float nd = fminf(d##i, t2); d##i = nd;                                   \
    if (nd > bestv) { bestv = nd; bestp = pbase + (i) * FTPB; } }
      X8(UPD8)
#undef UPD8
    }
    return;
  }

  // ===================== KNN (consumer) =====================
  const int qid = (bx - NFPSBLK) * KNNQPB + wid;   // 0..8191
  const int b   = qid >> 10;
  const float* __restrict__ c = coord + (size_t)b * NPTS * 3;

  // Spin until fps publishes this query's index (idx+1 encoding).
  int enc;
  for (;;) {
    enc = __hip_atomic_load(&s_idx_ws[qid], __ATOMIC_RELAXED,
                            __HIP_MEMORY_SCOPE_AGENT);
    if (enc != 0) break;
    __builtin_amdgcn_s_sleep(16);
  }
  const int sp = __builtin_amdgcn_readfirstlane(enc - 1);
  const int gq = b * NPTS + sp;
  const float qx = coord[(size_t)gq * 3 + 0];
  const float qy = coord[(size_t)gq * 3 + 1];
  const float qz = coord[(size_t)gq * 3 + 2];

  // Per-lane ascending top-8 (value, index), static indexing only.
  float lv[KLANE]; int li[KLANE];
  #pragma unroll
  for (int j = 0; j < KLANE; ++j) { lv[j] = 1e30f; li[j] = 0x7fffffff; }

  // Branchless sorted insert; strict < keeps equal-distance earlier (lower)
  // indices first, matching lax.top_k tie order.
#define INSERT(D2, P) \
  if ((D2) < lv[KLANE - 1]) { \
    _Pragma("unroll") \
    for (int j = KLANE - 1; j >= 1; --j) { \
      bool up = (D2) < lv[j - 1]; \
      float nv = up ? lv[j - 1] : (((D2) < lv[j]) ? (D2) : lv[j]); \
      int   ni = up ? li[j - 1] : (((D2) < lv[j]) ? (P)  : li[j]); \
      lv[j] = nv; li[j] = ni; \
    } \
    if ((D2) < lv[0]) { lv[0] = (D2); li[0] = (P); } \
  }

  for (int s = 0; s < NPTS / 256; ++s) {   // 128 iterations, 4 pts/lane
    int p = (s << 8) | (lane << 2);
    const float4* c4 = (const float4*)(c + (size_t)p * 3);
    float4 f0 = c4[0], f1 = c4[1], f2 = c4[2];
    float dA = dist2f(f0.x, f0.y, f0.z, qx, qy, qz);
    float dB = dist2f(f0.w, f1.x, f1.y, qx, qy, qz);
    float dC = dist2f(f1.z, f1.w, f2.x, qx, qy, qz);
    float dD = dist2f(f2.y, f2.z, f2.w, qx, qy, qz);
    INSERT(dA, p);
    INSERT(dB, p + 1);
    INSERT(dC, p + 2);
    INSERT(dD, p + 3);
  }
#undef INSERT

  // Extract the 32 globally smallest (ascending, tie -> lower index).
  // Round 0 is the query itself (d2 == 0), excluded from the angle mean
  // like angles[:, :, 1:].
  int nbp = 0;
  for (int r = 0; r < GSIZE; ++r) {
    float mv = lv[0]; int mp = li[0];
    #pragma unroll
    for (int m = 1; m < 64; m <<= 1) {
      float ov = __shfl_xor(mv, m, 64);
      int   op = __shfl_xor(mp, m, 64);
      if (ov < mv || (ov == mv && op < mp)) { mv = ov; mp = op; }
    }
    if (lane == r) nbp = mp;
    if (lv[0] == mv && li[0] == mp) {  // unique winner pops its head
      #pragma unroll
      for (int j = 0; j < KLANE - 1; ++j) { lv[j] = lv[j + 1]; li[j] = li[j + 1]; }
      lv[KLANE - 1] = 1e30f; li[KLANE - 1] = 0x7fffffff;
    }
  }

  // Angle for lanes 1..31: theta = 2*atan2(||a*|b| - |a|*b||, ||a*|b| + |a|*b||)
  const float* aRow = feat + (size_t)gq * FDIM;
  float my_a = (lane < FDIM) ? aRow[lane] : 0.0f;

  float ang = 0.0f;
  if (lane >= 1 && lane < GSIZE) {
    const float4* a4 = (const float4*)aRow;
    const float4* b4 = (const float4*)(feat + ((size_t)b * NPTS + nbp) * FDIM);
    float4 av[FDIM / 4], bv[FDIM / 4];
    float aa = 0.0f, bb = 0.0f;
    #pragma unroll
    for (int k = 0; k < FDIM / 4; ++k) {
      av[k] = a4[k]; bv[k] = b4[k];
      aa += av[k].x * av[k].x + av[k].y * av[k].y + av[k].z * av[k].z + av[k].w * av[k].w;
      bb += bv[k].x * bv[k].x + bv[k].y * bv[k].y + bv[k].z * bv[k].z + bv[k].w * bv[k].w;
    }
    float an = sqrtf(aa), bn = sqrtf(bb);
    float num2 = 0.0f, den2 = 0.0f;
    #pragma unroll
    for (int k = 0; k < FDIM / 4; ++k) {
      float n0 = av[k].x * bn - an * bv[k].x, dd0 = av[k].x * bn + an * bv[k].x;
      float n1 = av[k].y * bn - an * bv[k].y, dd1 = av[k].y * bn + an * bv[k].y;
      float n2 = av[k].z * bn - an * bv[k].z, dd2 = av[k].z * bn + an * bv[k].z;
      float n3 = av[k].w * bn - an * bv[k].w, dd3 = av[k].w * bn + an * bv[k].w;
      num2 += n0 * n0 + n1 * n1 + n2 * n2 + n3 * n3;
      den2 += dd0 * dd0 + dd1 * dd1 + dd2 * dd2 + dd3 * dd3;
    }
    ang = 2.0f * atan2f(sqrtf(num2), sqrtf(den2));
  }

  // Wave sum of the 31 angles -> p_curv everywhere.
  float tot = ang;
  #pragma unroll
  for (int m = 1; m < 64; m <<= 1) tot += __shfl_xor(tot, m, 64);
  float p_curv = tot / 31.0f;

  // Outputs (flat concatenation, all as float32).
  float* out_xyz  = out;                              // 8192*3
  float* out_feat = out + (size_t)BATCH * NGROUP * 3; // 8192*33
  float* out_sw   = out_feat + (size_t)BATCH * NGROUP * (FDIM + 1);
  float* out_lab  = out_sw  + (size_t)BATCH * NGROUP;
  float* out_sif  = out_lab + (size_t)BATCH * NGROUP;

  if (lane < FDIM)  out_feat[(size_t)qid * (FDIM + 1) + lane] = my_a;
  if (lane == FDIM) out_feat[(size_t)qid * (FDIM + 1) + FDIM] = p_curv;
  if (lane == 0) {
    out_xyz[(size_t)qid * 3 + 0] = qx;
    out_xyz[(size_t)qid * 3 + 1] = qy;
    out_xyz[(size_t)qid * 3 + 2] = qz;
    out_sw[qid]  = (p_curv > 0.087266f) ? 1.0f : 0.0f;
    out_lab[qid] = (float)labels[gq];
    out_sif[qid] = (float)gq;   // s_idx + b*N
  }
}

extern "C" void kernel_launch(void* const* d_in, const int* in_sizes, int n_in,
                              void* d_out, int out_size, void* d_ws, size_t ws_size,
                              hipStream_t stream) {
  const float* coord  = (const float*)d_in[0];
  const float* feat   = (const float*)d_in[1];
  const int*   labels = (const int*)d_in[2];

  // ws layout: [2][64] u64 ping-pong slots, then [8192] int s_idx (+1
  // encoded, 0 = unpublished). Both must start zeroed.
  unsigned long long* slots = (unsigned long long*)d_ws;
  int* s_idx_ws = (int*)((char*)d_ws +
                         2 * BATCH * NBLK * sizeof(unsigned long long));
  const size_t zbytes = 2 * BATCH * NBLK * sizeof(unsigned long long)
                      + (size_t)BATCH * NGROUP * sizeof(int);

  hipMemsetAsync(d_ws, 0, zbytes, stream);
  fused_kernel<<<NFPSBLK + NKNNBLK, FTPB, 0, stream>>>(
      coord, feat, labels, slots, s_idx_ws, (float*)d_out);
}